// Round 15
// baseline (3492.043 us; speedup 1.0000x reference)
//
#include <hip/hip_runtime.h>

typedef unsigned short u16;
typedef unsigned int u32;
typedef unsigned long long u64;
using f32x4 = __attribute__((ext_vector_type(4))) float;
using s16x8 = __attribute__((ext_vector_type(8))) short;
using u64x2 = __attribute__((ext_vector_type(2))) unsigned long long;

constexpr int Tn = 512, Bn = 64, Hn = 512, Gn = 2048, On = 128;
constexpr int NS = 16;  // gate-slice WGs per batch group
constexpr int NG = 4;   // batch groups (independent)

// -------- workspace layout (bytes), total ~166 MB --------
constexpr size_t HT_BYTES = (size_t)(Tn + 1) * Bn * Hn * 2;       // 33.6 MB
constexpr size_t XG_BYTES = (size_t)Tn * (size_t)Gn * Bn * 2;     // 128 MB
constexpr size_t WB_BYTES = (size_t)Gn * Hn * 2;                  // 2 MB
constexpr size_t OFF_PROG = 0;                                    // 1024 B (64 counters)
constexpr size_t OFF_CMID = 1024;
constexpr size_t OFF_HMID = OFF_CMID + (size_t)Bn * Hn * 4;
constexpr size_t OFF_WB1  = OFF_HMID + (size_t)Bn * Hn * 4;
constexpr size_t OFF_WB2  = OFF_WB1 + WB_BYTES;
constexpr size_t OFF_HT1  = OFF_WB2 + WB_BYTES;                   // trail, reused by layer 2
constexpr size_t OFF_XG   = OFF_HT1 + HT_BYTES;                   // xg1, overwritten in place by xg2

// -------- helpers --------
__device__ __forceinline__ u16 f2b(float f) {
  union { float f; unsigned u; } v; v.f = f;
  unsigned r = v.u + 0x7fffu + ((v.u >> 16) & 1u);
  return (u16)(r >> 16);
}
__device__ __forceinline__ float b2f(u16 u) {
  union { unsigned u; float f; } v; v.u = ((unsigned)u) << 16; return v.f;
}
__device__ __forceinline__ s16x8 pack8(float4 lo, float4 hi) {
  s16x8 r;
  r[0] = (short)f2b(lo.x); r[1] = (short)f2b(lo.y); r[2] = (short)f2b(lo.z); r[3] = (short)f2b(lo.w);
  r[4] = (short)f2b(hi.x); r[5] = (short)f2b(hi.y); r[6] = (short)f2b(hi.z); r[7] = (short)f2b(hi.w);
  return r;
}
__device__ __forceinline__ float sigm(float x) {
  float e = __builtin_amdgcn_exp2f(-1.4426950408889634f * x);
  return __builtin_amdgcn_rcpf(1.0f + e);
}
__device__ __forceinline__ float tanh_(float x) {
  float e = __builtin_amdgcn_exp2f(-2.885390081777927f * x);
  return __builtin_amdgcn_rcpf(1.0f + e) * 2.0f - 1.0f;
}
// agent-scope (device-coherent, IC-visible) relaxed atomics — the proven exchange path
__device__ __forceinline__ u64 ld64_sc(const u64* p) {
  return __hip_atomic_load(p, __ATOMIC_RELAXED, __HIP_MEMORY_SCOPE_AGENT);
}
__device__ __forceinline__ void st64_sc(u64* p, u64 v) {
  __hip_atomic_store(p, v, __ATOMIC_RELAXED, __HIP_MEMORY_SCOPE_AGENT);
}
__device__ __forceinline__ u32 ld32_sc(const u32* p) {
  return __hip_atomic_load(p, __ATOMIC_RELAXED, __HIP_MEMORY_SCOPE_AGENT);
}
__device__ __forceinline__ void st32_sc(u32* p, u32 v) {
  __hip_atomic_store(p, v, __ATOMIC_RELAXED, __HIP_MEMORY_SCOPE_AGENT);
}
__device__ __forceinline__ ushort4 u64_to_us4(u64 q) { union { u64 q; ushort4 v; } u; u.q = q; return u.v; }
__device__ __forceinline__ s16x8 two_u64_to_s16x8(u64 a, u64 b) {
  union { u64 q[2]; s16x8 v; } u; u.q[0] = a; u.q[1] = b; return u.v;
}

// -------- f32 -> bf16 bulk convert (W_ih pre-conversion) --------
__global__ __launch_bounds__(256)
void cvt_kernel(const float* __restrict__ in, u16* __restrict__ out, int n4) {
  const int i = blockIdx.x * 256 + threadIdx.x;
  if (i < n4) {
    float4 v = ((const float4*)in)[i];
    ushort4 o; o.x = f2b(v.x); o.y = f2b(v.y); o.z = f2b(v.z); o.w = f2b(v.w);
    ((ushort4*)out)[i] = o;
  }
}

// ================= proj core (R13 tile-major structure) =================
// xg[t][n][b] = A[m][:] . W[n][:] + bih[n] + bhh[n]; m = t*64+b; 128x128 tiles,
// tile = mb*16 + nb, WG strides by nwg (16 WGs share each A-panel concurrently -> IC hits).
// W: bf16 [2048][512]. AF32: A is f32 (x), plain loads, no gate.
// !AF32 (proj2): A = y1 trail slice; GATE on scan1 progress counters, then single sc1 reads.
// All xg stores are agent-scope 8B.
template<bool AF32>
__device__ __forceinline__ void proj_core(
    const int wg, const int nwg, const void* __restrict__ Ap,
    const u16* __restrict__ Wb, const float* __restrict__ bih,
    const float* __restrict__ bhh, u16* __restrict__ xg,
    volatile u32* __restrict__ prog)
{
  const int lane = threadIdx.x & 63, wave = threadIdx.x >> 6;
  const int lrow = lane & 15, lk8 = (lane >> 4) << 3;
  for (int tile = wg; tile < 4096; tile += nwg) {
    const int m0 = (tile >> 4) * 128 + (wave & 1) * 64;
    const int n0 = (tile & 15) * 128 + (wave >> 1) * 64;
    if constexpr (!AF32) {
      // gate: all 64 scan WGs past step 2*mb+2 -> y1 rows for this tile are published
      const u32 need = 2u * (u32)(tile >> 4) + 2u;
      while (true) {
        const u32 pv = ld32_sc((const u32*)&prog[lane]);
        if (__all(pv >= need)) break;
        __builtin_amdgcn_s_sleep(16);
      }
    }
    f32x4 acc[4][4] = {};
    for (int ks = 0; ks < 16; ++ks) {
      const int k0 = ks * 32 + lk8;
      s16x8 af[4], bfr[4];
      if constexpr (AF32) {
#pragma unroll
        for (int mt = 0; mt < 4; ++mt) {
          const float* ap = (const float*)Ap + (size_t)(m0 + mt * 16 + lrow) * Hn + k0;
          float4 lo = *(const float4*)ap, hi = *(const float4*)(ap + 4);
          af[mt] = pack8(lo, hi);
        }
      } else {
#pragma unroll
        for (int mt = 0; mt < 4; ++mt) {
          const u64* p = (const u64*)((const u16*)Ap + (size_t)(m0 + mt * 16 + lrow) * Hn + k0);
          af[mt] = two_u64_to_s16x8(ld64_sc(p), ld64_sc(p + 1));
        }
      }
#pragma unroll
      for (int nt = 0; nt < 4; ++nt)
        bfr[nt] = *(const s16x8*)(Wb + (size_t)(n0 + nt * 16 + lrow) * Hn + k0);
#pragma unroll
      for (int mt = 0; mt < 4; ++mt)
#pragma unroll
        for (int nt = 0; nt < 4; ++nt)
          acc[mt][nt] = __builtin_amdgcn_mfma_f32_16x16x32_bf16(af[mt], bfr[nt], acc[mt][nt], 0, 0, 0);
    }
    const int rbase = (lane >> 4) << 2;
#pragma unroll
    for (int nt = 0; nt < 4; ++nt) {
      const int n = n0 + nt * 16 + lrow;
      const float bias = bih[n] + bhh[n];
#pragma unroll
      for (int mt = 0; mt < 4; ++mt) {
        const int m = m0 + mt * 16 + rbase;
        const int t = m >> 6, b = m & 63;
        const u64 pv = (u64)f2b(acc[mt][nt][0] + bias)
                     | ((u64)f2b(acc[mt][nt][1] + bias) << 16)
                     | ((u64)f2b(acc[mt][nt][2] + bias) << 32)
                     | ((u64)f2b(acc[mt][nt][3] + bias) << 48);
        st64_sc((u64*)(xg + ((size_t)t * Gn + n) * Bn + b), pv);
      }
    }
  }
}

// ================= scan core (unfused, R5 protocol) =================
// ht: [T+1][B][H] bf16 trail, pre-poisoned 0xFF. Region t = h after step t-1.
// POLL_XG: xg produced in SAME dispatch -> sc1 + poison-poll xv slices.
// prog != nullptr: publish per-WG progress counter (prog[wg]=t at top of step t:
// bar3(t-1) drained region-t publishes, so prog=t implies region t visible).
template<bool POLL_XG>
__device__ __forceinline__ void scan_core(
    const int wgid, const u16* __restrict__ xg, const float* __restrict__ Whh,
    const float* __restrict__ hinit, const float* __restrict__ cinit,
    u16* __restrict__ ht, float* __restrict__ h_fin, float* __restrict__ c_fin,
    u32* __restrict__ prog)
{
  const int g = wgid >> 4, s = wgid & (NS - 1);
  const int tid = threadIdx.x;
  const int lane = tid & 63, w = tid >> 6;
  const int x16 = lane & 15, grp = lane >> 4;
  const int jj = x16 & 7;
  const int j0 = s * 32 + w * 8;
  const int brow = g * 16;
  const int bth = brow + grp * 4;

  __shared__ char hlds[16 * 1024];   // h(t) tile, XOR-swizzled 16B chunks
  __shared__ u16 hstage[16][32];     // publish staging (u64 writes via transpose)

  const size_t grow0 = (size_t)(x16 >> 3) * Hn + j0 + jj;        // gates i/f
  const size_t grow1 = (size_t)(2 + (x16 >> 3)) * Hn + j0 + jj;  // gates g/o
  s16x8 bwh[2][16];
#pragma unroll
  for (int nt = 0; nt < 2; ++nt) {
    const size_t grow = nt ? grow1 : grow0;
#pragma unroll
    for (int ks = 0; ks < 16; ++ks) {
      const float* wp = Whh + grow * Hn + ks * 32 + grp * 8;
      float4 lo = *(const float4*)wp, hi = *(const float4*)(wp + 4);
      bwh[nt][ks] = pack8(lo, hi);
    }
  }

  float c[4];
#pragma unroll
  for (int r = 0; r < 4; ++r) c[r] = cinit[(size_t)(bth + r) * Hn + j0 + jj];

  // publish region 0 slice from hinit (f32 -> bf16)
  if (tid < 128) {
    const int row = tid >> 3, cq = tid & 7;
    const float* hp = hinit + (size_t)(brow + row) * Hn + s * 32 + cq * 4;
    u64 v = (u64)f2b(hp[0]) | ((u64)f2b(hp[1]) << 16)
          | ((u64)f2b(hp[2]) << 32) | ((u64)f2b(hp[3]) << 48);
    st64_sc((u64*)(ht + (size_t)(brow + row) * Hn + s * 32 + cq * 4), v);
  }

  // prologue: xg[0] fragments (poll if same-dispatch producer)
  ushort4 xv0, xv1;
  {
    const u16* xa = xg + grow0 * Bn + bth;
    const u16* xb = xg + grow1 * Bn + bth;
    if constexpr (POLL_XG) {
      u64 a = ld64_sc((const u64*)xa), b = ld64_sc((const u64*)xb);
      while (a == ~0ull || b == ~0ull) {
        __builtin_amdgcn_s_sleep(2);
        if (a == ~0ull) a = ld64_sc((const u64*)xa);
        if (b == ~0ull) b = ld64_sc((const u64*)xb);
      }
      xv0 = u64_to_us4(a); xv1 = u64_to_us4(b);
    } else {
      xv0 = *(const ushort4*)xa; xv1 = *(const ushort4*)xb;
    }
  }

  for (int t = 0; t < Tn; ++t) {
    const u16* rt = ht + (size_t)t * Bn * Hn;
    // [A] h(t) poll loads — only outstanding vmem at loop top (besides prog store below)
    const u64* p0 = (const u64*)(rt + (size_t)(brow + (tid >> 6)) * Hn) + ((tid & 63) << 1);
    u64 v[8];
#pragma unroll
    for (int i = 0; i < 4; ++i) {
      v[2 * i]     = ld64_sc(p0 + i * 512);
      v[2 * i + 1] = ld64_sc(p0 + i * 512 + 1);
    }
    // progress counter AFTER the poll loads (youngest vmem -> [C]'s waits stay vmcnt(1);
    // its ack is long done by bar1)
    if (prog != nullptr && t > 0 && tid == 0) st32_sc(prog + wgid, (u32)t);
    // [C] per-chunk retry (R5 protocol)
    while (true) {
      bool all = true;
#pragma unroll
      for (int i = 0; i < 8; ++i) all = all && (v[i] != ~0ull);
      if (all) break;
      __builtin_amdgcn_s_sleep(1);
#pragma unroll
      for (int i = 0; i < 4; ++i) {
        if (v[2 * i]     == ~0ull) v[2 * i]     = ld64_sc(p0 + i * 512);
        if (v[2 * i + 1] == ~0ull) v[2 * i + 1] = ld64_sc(p0 + i * 512 + 1);
      }
    }
    // [D] stage h(t) into LDS (16B-chunk XOR swizzle)
    {
      const int row = tid >> 6, ci = tid & 63;
#pragma unroll
      for (int i = 0; i < 4; ++i) {
        const int rr = row + 4 * i;
        u64x2 q; q[0] = v[2 * i]; q[1] = v[2 * i + 1];
        *(u64x2*)(hlds + rr * 1024 + ((ci ^ (rr & 7)) * 16)) = q;
      }
    }
    __syncthreads();   // bar1
    // [E] recurrent MFMAs; acc init = xg slice (bias folded by proj)
    f32x4 acc0, acc1;
    acc0[0] = b2f(xv0.x); acc0[1] = b2f(xv0.y); acc0[2] = b2f(xv0.z); acc0[3] = b2f(xv0.w);
    acc1[0] = b2f(xv1.x); acc1[1] = b2f(xv1.y); acc1[2] = b2f(xv1.z); acc1[3] = b2f(xv1.w);
#pragma unroll
    for (int ks = 0; ks < 16; ++ks) {
      const s16x8 a = *(const s16x8*)(hlds + x16 * 1024 + ((((ks << 2) + grp) ^ jj) * 16));
      acc0 = __builtin_amdgcn_mfma_f32_16x16x32_bf16(a, bwh[0][ks], acc0, 0, 0, 0);
      acc1 = __builtin_amdgcn_mfma_f32_16x16x32_bf16(a, bwh[1][ks], acc1, 0, 0, 0);
    }
    // [F] gates: tile0 rows i(j)/f(j); tile1 g(j)/o(j); pair via shfl_xor(8)
    float hv[4];
#pragma unroll
    for (int r = 0; r < 4; ++r) {
      const float p0v = acc0[r], p1v = acc1[r];
      const float q0 = __shfl_xor(p0v, 8, 64);
      const float q1 = __shfl_xor(p1v, 8, 64);
      const bool lo = (x16 < 8);
      const float gi = lo ? p0v : q0;
      const float gf = lo ? q0 : p0v;
      const float gg = lo ? p1v : q1;
      const float go = lo ? q1 : p1v;
      const float cn = sigm(gf) * c[r] + sigm(gi) * tanh_(gg);
      c[r] = cn;
      hv[r] = sigm(go) * tanh_(cn);
    }
    if (t == Tn - 1 && x16 < 8) {
#pragma unroll
      for (int r = 0; r < 4; ++r) {
        h_fin[(size_t)(bth + r) * Hn + j0 + jj] = hv[r];
        c_fin[(size_t)(bth + r) * Hn + j0 + jj] = c[r];
      }
    }
    // [F2] in-register 4x4 transpose (masks 1,2 stay inside x16<8); [G] u64 hstage write
    {
      float a0 = hv[0], a1 = hv[1], a2 = hv[2], a3 = hv[3];
      const int p = x16 & 3;
      float tvu;
      tvu = (p & 1) ? a0 : a1;  tvu = __shfl_xor(tvu, 1, 64);
      if (p & 1) a0 = tvu; else a1 = tvu;
      tvu = (p & 1) ? a2 : a3;  tvu = __shfl_xor(tvu, 1, 64);
      if (p & 1) a2 = tvu; else a3 = tvu;
      tvu = (p & 2) ? a0 : a2;  tvu = __shfl_xor(tvu, 2, 64);
      if (p & 2) a0 = tvu; else a2 = tvu;
      tvu = (p & 2) ? a1 : a3;  tvu = __shfl_xor(tvu, 2, 64);
      if (p & 2) a1 = tvu; else a3 = tvu;
      if (x16 < 8) {
        const int cc = (x16 >> 2) & 1;
        const u64 yv = (u64)f2b(a0) | ((u64)f2b(a1) << 16)
                     | ((u64)f2b(a2) << 32) | ((u64)f2b(a3) << 48);
        *(u64*)&hstage[grp * 4 + p][w * 8 + cc * 4] = yv;
      }
    }
    __syncthreads();   // bar2
    // [I] publish region t+1: 128 coalesced 8B agent-scope stores (64B segments)
    if (!(tid & 1)) {
      const int q = tid >> 1, row = q >> 3, cq = q & 7;
      const u64 yv = *(const u64*)&hstage[row][cq * 4];
      st64_sc((u64*)(ht + (size_t)(t + 1) * Bn * Hn + (size_t)(brow + row) * Hn + s * 32 + cq * 4), yv);
    }
    // [H] xg[t+1] prefetch in the publish->visibility hop shadow
    const int tn2 = (t + 1 < Tn) ? t + 1 : t;
    {
      const u16* xa = xg + ((size_t)tn2 * Gn + grow0) * Bn + bth;
      const u16* xb = xg + ((size_t)tn2 * Gn + grow1) * Bn + bth;
      if constexpr (POLL_XG) {
        u64 a = ld64_sc((const u64*)xa), b = ld64_sc((const u64*)xb);
        while (a == ~0ull || b == ~0ull) {
          __builtin_amdgcn_s_sleep(2);
          if (a == ~0ull) a = ld64_sc((const u64*)xa);
          if (b == ~0ull) b = ld64_sc((const u64*)xb);
        }
        xv0 = u64_to_us4(a); xv1 = u64_to_us4(b);
      } else {
        xv0 = *(const ushort4*)xa; xv1 = *(const ushort4*)xb;
      }
    }
    __syncthreads();   // bar3: drains everything -> loop invariant restored
  }
  // final progress: region Tn published & drained (bar3 of last step)
  if (prog != nullptr && tid == 0) st32_sc(prog + wgid, (u32)Tn);
}

// ================= kernels =================
// One dispatch, three roles: scan1 (WG 0-63) || proj1 (64-159) || proj2 (160-255).
// proj2 writes xg2 IN PLACE over xg1 — gate prog>=2mb+2 implies every scan WG already
// consumed xg1[2mb+1] (prefetched at tail of step 2mb, drained by bar3).
__global__ __launch_bounds__(256, 1)
void mega_full(const float* __restrict__ x,
               const u16* __restrict__ Wb1, const float* __restrict__ bih1, const float* __restrict__ bhh1,
               const float* __restrict__ Whh1, const float* __restrict__ h0, const float* __restrict__ c0,
               u16* __restrict__ ht1, u16* __restrict__ xg,
               const u16* __restrict__ Wb2, const float* __restrict__ bih2, const float* __restrict__ bhh2,
               float* __restrict__ h_mid, float* __restrict__ c_mid, u32* __restrict__ prog)
{
  const int bid = blockIdx.x;
  if (bid < 64)
    scan_core<true>(bid, xg, Whh1, h0, c0, ht1, h_mid, c_mid, prog);
  else if (bid < 160)
    proj_core<true>(bid - 64, 96, x, Wb1, bih1, bhh1, xg, nullptr);
  else
    proj_core<false>(bid - 160, 96, ht1 + (size_t)Bn * Hn, Wb2, bih2, bhh2, xg, prog);
}

__global__ __launch_bounds__(256, 1)
void scan_plain(const u16* __restrict__ xg, const float* __restrict__ Whh,
                const float* __restrict__ hinit, const float* __restrict__ cinit,
                u16* __restrict__ ht, float* __restrict__ h_fin, float* __restrict__ c_fin)
{
  scan_core<false>(blockIdx.x, xg, Whh, hinit, cinit, ht, h_fin, c_fin, nullptr);
}

// -------- output head --------
__global__ __launch_bounds__(128)
void out_kernel(const float* __restrict__ h2, const float* __restrict__ Wout,
                const float* __restrict__ bout, float* __restrict__ out)
{
  const int b = blockIdx.x, o = threadIdx.x;
  const float4* hp = (const float4*)(h2 + (size_t)b * Hn);
  const float4* wp = (const float4*)(Wout + (size_t)o * Hn);
  float acc = 0.f;
#pragma unroll 4
  for (int k = 0; k < Hn / 4; ++k) {
    float4 h4 = hp[k], w4 = wp[k];
    acc += h4.x * w4.x + h4.y * w4.y + h4.z * w4.z + h4.w * w4.w;
  }
  out[(size_t)b * On + o] = acc + bout[o];
}

extern "C" void kernel_launch(void* const* d_in, const int* in_sizes, int n_in,
                              void* d_out, int out_size, void* d_ws, size_t ws_size,
                              hipStream_t stream) {
  const float* x     = (const float*)d_in[0];
  const float* h0    = (const float*)d_in[1];
  const float* c0    = (const float*)d_in[2];
  const float* W_ih1 = (const float*)d_in[3];
  const float* W_hh1 = (const float*)d_in[4];
  const float* b_ih1 = (const float*)d_in[5];
  const float* b_hh1 = (const float*)d_in[6];
  const float* W_ih2 = (const float*)d_in[7];
  const float* W_hh2 = (const float*)d_in[8];
  const float* b_ih2 = (const float*)d_in[9];
  const float* b_hh2 = (const float*)d_in[10];
  const float* W_out = (const float*)d_in[11];
  const float* b_out = (const float*)d_in[12];

  float* out    = (float*)d_out;
  float* h2_out = out + (size_t)Bn * On;
  float* c2_out = h2_out + (size_t)Bn * Hn;

  char* w = (char*)d_ws;
  u32*   prog  = (u32*)(w + OFF_PROG);
  float* c_mid = (float*)(w + OFF_CMID);
  float* h_mid = (float*)(w + OFF_HMID);
  u16*   Wb1   = (u16*)(w + OFF_WB1);
  u16*   Wb2   = (u16*)(w + OFF_WB2);
  u16*   ht1   = (u16*)(w + OFF_HT1);
  u16*   xg    = (u16*)(w + OFF_XG);

  const int nw4 = Gn * Hn / 4;

  hipMemsetAsync(w, 0, 1024, stream);            // zero progress counters (replay-safe)
  hipMemsetAsync(ht1, 0xFF, HT_BYTES, stream);   // trail poison (0xFFFF = NaN sentinel)
  hipMemsetAsync(xg, 0xFF, XG_BYTES, stream);    // xg poison (scan1 polls it)
  cvt_kernel<<<(nw4 + 255) / 256, 256, 0, stream>>>(W_ih1, Wb1, nw4);
  cvt_kernel<<<(nw4 + 255) / 256, 256, 0, stream>>>(W_ih2, Wb2, nw4);

  // Phase 1 (one dispatch): scan1 || proj1 || proj2 (counter-gated, in-place xg overwrite).
  mega_full<<<256, 256, 0, stream>>>(x, Wb1, b_ih1, b_hh1, W_hh1, h0, c0,
                                     ht1, xg, Wb2, b_ih2, b_hh2, h_mid, c_mid, prog);
  // Phase 2: ht1 fully dead (proj2 consumed y1) -> re-poison and reuse as layer-2 trail.
  hipMemsetAsync(ht1, 0xFF, HT_BYTES, stream);
  scan_plain<<<NG * NS, 256, 0, stream>>>(xg, W_hh2, h_mid, c_mid, ht1, h2_out, c2_out);
  out_kernel<<<Bn, 128, 0, stream>>>(h2_out, W_out, b_out, out);
}

// Round 16
// 2616.904 us; speedup vs baseline: 1.3344x; 1.3344x over previous
//
#include <hip/hip_runtime.h>

typedef unsigned short u16;
typedef unsigned int u32;
typedef unsigned long long u64;
using f32x4 = __attribute__((ext_vector_type(4))) float;
using s16x8 = __attribute__((ext_vector_type(8))) short;
using u32x4 = __attribute__((ext_vector_type(4))) unsigned int;
using u64x2 = __attribute__((ext_vector_type(2))) unsigned long long;

constexpr int Tn = 512, Bn = 64, Hn = 512, Gn = 2048, On = 128;
constexpr int NS = 16;  // gate-slice WGs per batch group
constexpr int NG = 4;   // batch groups (independent)

// -------- workspace layout (bytes), total ~166 MB --------
constexpr size_t HT_BYTES = (size_t)(Tn + 1) * Bn * Hn * 2;       // 33.6 MB
constexpr size_t XG_BYTES = (size_t)Tn * (size_t)Gn * Bn * 2;     // 128 MB
constexpr size_t WB_BYTES = (size_t)Gn * Hn * 2;                  // 2 MB
constexpr size_t OFF_CMID = 0;
constexpr size_t OFF_HMID = OFF_CMID + (size_t)Bn * Hn * 4;
constexpr size_t OFF_WB1  = OFF_HMID + (size_t)Bn * Hn * 4;
constexpr size_t OFF_WB2  = OFF_WB1 + WB_BYTES;
constexpr size_t OFF_HT1  = OFF_WB2 + WB_BYTES;                   // trail, reused by layer 2
constexpr size_t OFF_XG   = OFF_HT1 + HT_BYTES;                   // xg1, overwritten in place by xg2

// -------- helpers --------
__device__ __forceinline__ u16 f2b(float f) {
  union { float f; unsigned u; } v; v.f = f;
  unsigned r = v.u + 0x7fffu + ((v.u >> 16) & 1u);
  return (u16)(r >> 16);
}
__device__ __forceinline__ float b2f(u16 u) {
  union { unsigned u; float f; } v; v.u = ((unsigned)u) << 16; return v.f;
}
__device__ __forceinline__ s16x8 pack8(float4 lo, float4 hi) {
  s16x8 r;
  r[0] = (short)f2b(lo.x); r[1] = (short)f2b(lo.y); r[2] = (short)f2b(lo.z); r[3] = (short)f2b(lo.w);
  r[4] = (short)f2b(hi.x); r[5] = (short)f2b(hi.y); r[6] = (short)f2b(hi.z); r[7] = (short)f2b(hi.w);
  return r;
}
__device__ __forceinline__ float sigm(float x) {
  float e = __builtin_amdgcn_exp2f(-1.4426950408889634f * x);
  return __builtin_amdgcn_rcpf(1.0f + e);
}
__device__ __forceinline__ float tanh_(float x) {
  float e = __builtin_amdgcn_exp2f(-2.885390081777927f * x);
  return __builtin_amdgcn_rcpf(1.0f + e) * 2.0f - 1.0f;
}
// agent-scope (device-coherent, IC-visible) relaxed atomics — the proven exchange path
__device__ __forceinline__ u64 ld64_sc(const u64* p) {
  return __hip_atomic_load(p, __ATOMIC_RELAXED, __HIP_MEMORY_SCOPE_AGENT);
}
__device__ __forceinline__ void st64_sc(u64* p, u64 v) {
  __hip_atomic_store(p, v, __ATOMIC_RELAXED, __HIP_MEMORY_SCOPE_AGENT);
}
__device__ __forceinline__ ushort4 u64_to_us4(u64 q) { union { u64 q; ushort4 v; } u; u.q = q; return u.v; }
__device__ __forceinline__ s16x8 u32x4_to_s16x8(u32x4 a) { union { u32x4 a; s16x8 v; } u; u.a = a; return u.v; }

// -------- f32 -> bf16 bulk convert (W_ih pre-conversion) --------
__global__ __launch_bounds__(256)
void cvt_kernel(const float* __restrict__ in, u16* __restrict__ out, int n4) {
  const int i = blockIdx.x * 256 + threadIdx.x;
  if (i < n4) {
    float4 v = ((const float4*)in)[i];
    ushort4 o; o.x = f2b(v.x); o.y = f2b(v.y); o.z = f2b(v.z); o.w = f2b(v.w);
    ((ushort4*)out)[i] = o;
  }
}

// ================= proj core (R13 tile-major, distributed data-polls) =================
// xg[t][n][b] = A[m][:] . W[n][:] + bih[n] + bhh[n]; m = t*64+b; 128x128 tiles,
// tile = mb*16 + nb, WG strides by nwg (16 WGs share each A-panel concurrently -> IC hits).
// W: bf16 [2048][512] direct loads. AF32: A is f32 (x), plain loads.
// !AF32 (proj2): A = y1 trail slice, poison-polled sc1 per k-step (spread over data lines).
// All xg stores are agent-scope 8B.
template<bool AF32>
__device__ __forceinline__ void proj_core(
    const int wg, const int nwg, const void* __restrict__ Ap,
    const u16* __restrict__ Wb, const float* __restrict__ bih,
    const float* __restrict__ bhh, u16* __restrict__ xg)
{
  const int lane = threadIdx.x & 63, wave = threadIdx.x >> 6;
  const int lrow = lane & 15, lk8 = (lane >> 4) << 3;
  for (int tile = wg; tile < 4096; tile += nwg) {
    const int m0 = (tile >> 4) * 128 + (wave & 1) * 64;
    const int n0 = (tile & 15) * 128 + (wave >> 1) * 64;
    f32x4 acc[4][4] = {};
    for (int ks = 0; ks < 16; ++ks) {
      const int k0 = ks * 32 + lk8;
      s16x8 af[4], bfr[4];
      if constexpr (AF32) {
#pragma unroll
        for (int mt = 0; mt < 4; ++mt) {
          const float* ap = (const float*)Ap + (size_t)(m0 + mt * 16 + lrow) * Hn + k0;
          float4 lo = *(const float4*)ap, hi = *(const float4*)(ap + 4);
          af[mt] = pack8(lo, hi);
        }
      } else {
        u32x4 a4[4];
        const char* pa0 = (const char*)((const u16*)Ap + (size_t)(m0 + 0 * 16 + lrow) * Hn + k0);
        const char* pa1 = (const char*)((const u16*)Ap + (size_t)(m0 + 1 * 16 + lrow) * Hn + k0);
        const char* pa2 = (const char*)((const u16*)Ap + (size_t)(m0 + 2 * 16 + lrow) * Hn + k0);
        const char* pa3 = (const char*)((const u16*)Ap + (size_t)(m0 + 3 * 16 + lrow) * Hn + k0);
        asm volatile("global_load_dwordx4 %0, %1, off sc1" : "=v"(a4[0]) : "v"(pa0) : "memory");
        asm volatile("global_load_dwordx4 %0, %1, off sc1" : "=v"(a4[1]) : "v"(pa1) : "memory");
        asm volatile("global_load_dwordx4 %0, %1, off sc1" : "=v"(a4[2]) : "v"(pa2) : "memory");
        asm volatile("global_load_dwordx4 %0, %1, off sc1" : "=v"(a4[3]) : "v"(pa3) : "memory");
        asm volatile("s_waitcnt vmcnt(0)" ::: "memory");
        // 8B publish units -> per-dword check is tear-free; genuine bf16 never 0xFFFF
        while (true) {
          bool bad = false;
#pragma unroll
          for (int mt = 0; mt < 4; ++mt)
#pragma unroll
            for (int d = 0; d < 4; ++d) bad = bad | (a4[mt][d] == 0xFFFFFFFFu);
          if (!bad) break;
          __builtin_amdgcn_s_sleep(8);   // throttled; polls spread over y1 data lines
          asm volatile("global_load_dwordx4 %0, %1, off sc1" : "=v"(a4[0]) : "v"(pa0) : "memory");
          asm volatile("global_load_dwordx4 %0, %1, off sc1" : "=v"(a4[1]) : "v"(pa1) : "memory");
          asm volatile("global_load_dwordx4 %0, %1, off sc1" : "=v"(a4[2]) : "v"(pa2) : "memory");
          asm volatile("global_load_dwordx4 %0, %1, off sc1" : "=v"(a4[3]) : "v"(pa3) : "memory");
          asm volatile("s_waitcnt vmcnt(0)" ::: "memory");
        }
#pragma unroll
        for (int mt = 0; mt < 4; ++mt) af[mt] = u32x4_to_s16x8(a4[mt]);
      }
#pragma unroll
      for (int nt = 0; nt < 4; ++nt)
        bfr[nt] = *(const s16x8*)(Wb + (size_t)(n0 + nt * 16 + lrow) * Hn + k0);
#pragma unroll
      for (int mt = 0; mt < 4; ++mt)
#pragma unroll
        for (int nt = 0; nt < 4; ++nt)
          acc[mt][nt] = __builtin_amdgcn_mfma_f32_16x16x32_bf16(af[mt], bfr[nt], acc[mt][nt], 0, 0, 0);
    }
    const int rbase = (lane >> 4) << 2;
#pragma unroll
    for (int nt = 0; nt < 4; ++nt) {
      const int n = n0 + nt * 16 + lrow;
      const float bias = bih[n] + bhh[n];
#pragma unroll
      for (int mt = 0; mt < 4; ++mt) {
        const int m = m0 + mt * 16 + rbase;
        const int t = m >> 6, b = m & 63;
        const u64 pv = (u64)f2b(acc[mt][nt][0] + bias)
                     | ((u64)f2b(acc[mt][nt][1] + bias) << 16)
                     | ((u64)f2b(acc[mt][nt][2] + bias) << 32)
                     | ((u64)f2b(acc[mt][nt][3] + bias) << 48);
        st64_sc((u64*)(xg + ((size_t)t * Gn + n) * Bn + b), pv);
      }
    }
  }
}

// ================= scan core (R5 protocol, bar3 removed via hstage double-buffer) =================
// ht: [T+1][B][H] bf16 trail, pre-poisoned 0xFF. Region t = h after step t-1.
// POLL_XG: xg produced in SAME dispatch -> sc1 + poison-poll xv slices.
// Step tail issues publish stores + xg prefetch WITHOUT draining; next step's poll
// check drains all three groups together (overlapped, pays max not sum).
// hlds WAR: protected by bar2 (all [E] reads precede bar2; next [D] write is after
// the following bar2-passage). hstage WAR: double-buffered by t&1 (two barriers
// separate [I](t) reads from [G](t+2) writes to the same buffer).
template<bool POLL_XG>
__device__ __forceinline__ void scan_core(
    const int wgid, const u16* __restrict__ xg, const float* __restrict__ Whh,
    const float* __restrict__ hinit, const float* __restrict__ cinit,
    u16* __restrict__ ht, float* __restrict__ h_fin, float* __restrict__ c_fin)
{
  const int g = wgid >> 4, s = wgid & (NS - 1);
  const int tid = threadIdx.x;
  const int lane = tid & 63, w = tid >> 6;
  const int x16 = lane & 15, grp = lane >> 4;
  const int jj = x16 & 7;
  const int j0 = s * 32 + w * 8;
  const int brow = g * 16;
  const int bth = brow + grp * 4;

  __shared__ char hlds[16 * 1024];      // h(t) tile, XOR-swizzled 16B chunks
  __shared__ u16 hstage[2][16][32];     // publish staging, double-buffered by t&1

  const size_t grow0 = (size_t)(x16 >> 3) * Hn + j0 + jj;        // gates i/f
  const size_t grow1 = (size_t)(2 + (x16 >> 3)) * Hn + j0 + jj;  // gates g/o
  s16x8 bwh[2][16];
#pragma unroll
  for (int nt = 0; nt < 2; ++nt) {
    const size_t grow = nt ? grow1 : grow0;
#pragma unroll
    for (int ks = 0; ks < 16; ++ks) {
      const float* wp = Whh + grow * Hn + ks * 32 + grp * 8;
      float4 lo = *(const float4*)wp, hi = *(const float4*)(wp + 4);
      bwh[nt][ks] = pack8(lo, hi);
    }
  }

  float c[4];
#pragma unroll
  for (int r = 0; r < 4; ++r) c[r] = cinit[(size_t)(bth + r) * Hn + j0 + jj];

  // publish region 0 slice from hinit (f32 -> bf16)
  if (tid < 128) {
    const int row = tid >> 3, cq = tid & 7;
    const float* hp = hinit + (size_t)(brow + row) * Hn + s * 32 + cq * 4;
    u64 v = (u64)f2b(hp[0]) | ((u64)f2b(hp[1]) << 16)
          | ((u64)f2b(hp[2]) << 32) | ((u64)f2b(hp[3]) << 48);
    st64_sc((u64*)(ht + (size_t)(brow + row) * Hn + s * 32 + cq * 4), v);
  }

  // prologue: xg[0] fragments (poll if same-dispatch producer)
  ushort4 xv0, xv1;
  {
    const u16* xa = xg + grow0 * Bn + bth;
    const u16* xb = xg + grow1 * Bn + bth;
    if constexpr (POLL_XG) {
      u64 a = ld64_sc((const u64*)xa), b = ld64_sc((const u64*)xb);
      while (a == ~0ull || b == ~0ull) {
        __builtin_amdgcn_s_sleep(2);
        if (a == ~0ull) a = ld64_sc((const u64*)xa);
        if (b == ~0ull) b = ld64_sc((const u64*)xb);
      }
      xv0 = u64_to_us4(a); xv1 = u64_to_us4(b);
    } else {
      xv0 = *(const ushort4*)xa; xv1 = *(const ushort4*)xb;
    }
  }

  for (int t = 0; t < Tn; ++t) {
    const u16* rt = ht + (size_t)t * Bn * Hn;
    // [A] h(t) poll loads — overlap with still-in-flight publish/prefetch from step t-1
    const u64* p0 = (const u64*)(rt + (size_t)(brow + (tid >> 6)) * Hn) + ((tid & 63) << 1);
    u64 v[8];
#pragma unroll
    for (int i = 0; i < 4; ++i) {
      v[2 * i]     = ld64_sc(p0 + i * 512);
      v[2 * i + 1] = ld64_sc(p0 + i * 512 + 1);
    }
    // [C] per-chunk retry (R5 protocol)
    while (true) {
      bool all = true;
#pragma unroll
      for (int i = 0; i < 8; ++i) all = all && (v[i] != ~0ull);
      if (all) break;
      __builtin_amdgcn_s_sleep(1);
#pragma unroll
      for (int i = 0; i < 4; ++i) {
        if (v[2 * i]     == ~0ull) v[2 * i]     = ld64_sc(p0 + i * 512);
        if (v[2 * i + 1] == ~0ull) v[2 * i + 1] = ld64_sc(p0 + i * 512 + 1);
      }
    }
    // [D] stage h(t) into LDS (16B-chunk XOR swizzle)
    {
      const int row = tid >> 6, ci = tid & 63;
#pragma unroll
      for (int i = 0; i < 4; ++i) {
        const int rr = row + 4 * i;
        u64x2 q; q[0] = v[2 * i]; q[1] = v[2 * i + 1];
        *(u64x2*)(hlds + rr * 1024 + ((ci ^ (rr & 7)) * 16)) = q;
      }
    }
    __syncthreads();   // bar1
    // [E] recurrent MFMAs; acc init = xg slice (bias folded by proj)
    f32x4 acc0, acc1;
    acc0[0] = b2f(xv0.x); acc0[1] = b2f(xv0.y); acc0[2] = b2f(xv0.z); acc0[3] = b2f(xv0.w);
    acc1[0] = b2f(xv1.x); acc1[1] = b2f(xv1.y); acc1[2] = b2f(xv1.z); acc1[3] = b2f(xv1.w);
#pragma unroll
    for (int ks = 0; ks < 16; ++ks) {
      const s16x8 a = *(const s16x8*)(hlds + x16 * 1024 + ((((ks << 2) + grp) ^ jj) * 16));
      acc0 = __builtin_amdgcn_mfma_f32_16x16x32_bf16(a, bwh[0][ks], acc0, 0, 0, 0);
      acc1 = __builtin_amdgcn_mfma_f32_16x16x32_bf16(a, bwh[1][ks], acc1, 0, 0, 0);
    }
    // [F] gates: tile0 rows i(j)/f(j); tile1 g(j)/o(j); pair via shfl_xor(8)
    float hv[4];
#pragma unroll
    for (int r = 0; r < 4; ++r) {
      const float p0v = acc0[r], p1v = acc1[r];
      const float q0 = __shfl_xor(p0v, 8, 64);
      const float q1 = __shfl_xor(p1v, 8, 64);
      const bool lo = (x16 < 8);
      const float gi = lo ? p0v : q0;
      const float gf = lo ? q0 : p0v;
      const float gg = lo ? p1v : q1;
      const float go = lo ? q1 : p1v;
      const float cn = sigm(gf) * c[r] + sigm(gi) * tanh_(gg);
      c[r] = cn;
      hv[r] = sigm(go) * tanh_(cn);
    }
    if (t == Tn - 1 && x16 < 8) {
#pragma unroll
      for (int r = 0; r < 4; ++r) {
        h_fin[(size_t)(bth + r) * Hn + j0 + jj] = hv[r];
        c_fin[(size_t)(bth + r) * Hn + j0 + jj] = c[r];
      }
    }
    // [F2] in-register 4x4 transpose (masks 1,2 stay inside x16<8); [G] u64 hstage write
    {
      float a0 = hv[0], a1 = hv[1], a2 = hv[2], a3 = hv[3];
      const int p = x16 & 3;
      float tvu;
      tvu = (p & 1) ? a0 : a1;  tvu = __shfl_xor(tvu, 1, 64);
      if (p & 1) a0 = tvu; else a1 = tvu;
      tvu = (p & 1) ? a2 : a3;  tvu = __shfl_xor(tvu, 1, 64);
      if (p & 1) a2 = tvu; else a3 = tvu;
      tvu = (p & 2) ? a0 : a2;  tvu = __shfl_xor(tvu, 2, 64);
      if (p & 2) a0 = tvu; else a2 = tvu;
      tvu = (p & 2) ? a1 : a3;  tvu = __shfl_xor(tvu, 2, 64);
      if (p & 2) a1 = tvu; else a3 = tvu;
      if (x16 < 8) {
        const int cc = (x16 >> 2) & 1;
        const u64 yv = (u64)f2b(a0) | ((u64)f2b(a1) << 16)
                     | ((u64)f2b(a2) << 32) | ((u64)f2b(a3) << 48);
        *(u64*)&hstage[t & 1][grp * 4 + p][w * 8 + cc * 4] = yv;
      }
    }
    __syncthreads();   // bar2 (the only barrier gating the publish)
    // [I] publish region t+1: 128 coalesced 8B agent-scope stores (64B segments).
    // NOT drained here — the ack overlaps the next step's poll latency.
    if (!(tid & 1)) {
      const int q = tid >> 1, row = q >> 3, cq = q & 7;
      const u64 yv = *(const u64*)&hstage[t & 1][row][cq * 4];
      st64_sc((u64*)(ht + (size_t)(t + 1) * Bn * Hn + (size_t)(brow + row) * Hn + s * 32 + cq * 4), yv);
    }
    // [H] xg[t+1] prefetch, also left in flight into the next poll drain
    const int tn2 = (t + 1 < Tn) ? t + 1 : t;
    {
      const u16* xa = xg + ((size_t)tn2 * Gn + grow0) * Bn + bth;
      const u16* xb = xg + ((size_t)tn2 * Gn + grow1) * Bn + bth;
      if constexpr (POLL_XG) {
        u64 a = ld64_sc((const u64*)xa), b = ld64_sc((const u64*)xb);
        while (a == ~0ull || b == ~0ull) {
          __builtin_amdgcn_s_sleep(2);
          if (a == ~0ull) a = ld64_sc((const u64*)xa);
          if (b == ~0ull) b = ld64_sc((const u64*)xb);
        }
        xv0 = u64_to_us4(a); xv1 = u64_to_us4(b);
      } else {
        xv0 = *(const ushort4*)xa; xv1 = *(const ushort4*)xb;
      }
    }
    // no bar3: hlds WAR covered by bar2; hstage double-buffered
  }
}

// ================= kernels =================
// One dispatch, three roles: scan1 (WG 0-63) || proj1 (64-159) || proj2 (160-255).
// proj2 writes xg2 IN PLACE over xg1 — its data-poll on y1[t] succeeds only after
// scan1 published region t+1, by which point xg1[t] was already consumed.
__global__ __launch_bounds__(256, 1)
void mega_full(const float* __restrict__ x,
               const u16* __restrict__ Wb1, const float* __restrict__ bih1, const float* __restrict__ bhh1,
               const float* __restrict__ Whh1, const float* __restrict__ h0, const float* __restrict__ c0,
               u16* __restrict__ ht1, u16* __restrict__ xg,
               const u16* __restrict__ Wb2, const float* __restrict__ bih2, const float* __restrict__ bhh2,
               float* __restrict__ h_mid, float* __restrict__ c_mid)
{
  const int bid = blockIdx.x;
  if (bid < 64)
    scan_core<true>(bid, xg, Whh1, h0, c0, ht1, h_mid, c_mid);
  else if (bid < 160)
    proj_core<true>(bid - 64, 96, x, Wb1, bih1, bhh1, xg);
  else
    proj_core<false>(bid - 160, 96, ht1 + (size_t)Bn * Hn, Wb2, bih2, bhh2, xg);
}

__global__ __launch_bounds__(256, 1)
void scan_plain(const u16* __restrict__ xg, const float* __restrict__ Whh,
                const float* __restrict__ hinit, const float* __restrict__ cinit,
                u16* __restrict__ ht, float* __restrict__ h_fin, float* __restrict__ c_fin)
{
  scan_core<false>(blockIdx.x, xg, Whh, hinit, cinit, ht, h_fin, c_fin);
}

// -------- output head --------
__global__ __launch_bounds__(128)
void out_kernel(const float* __restrict__ h2, const float* __restrict__ Wout,
                const float* __restrict__ bout, float* __restrict__ out)
{
  const int b = blockIdx.x, o = threadIdx.x;
  const float4* hp = (const float4*)(h2 + (size_t)b * Hn);
  const float4* wp = (const float4*)(Wout + (size_t)o * Hn);
  float acc = 0.f;
#pragma unroll 4
  for (int k = 0; k < Hn / 4; ++k) {
    float4 h4 = hp[k], w4 = wp[k];
    acc += h4.x * w4.x + h4.y * w4.y + h4.z * w4.z + h4.w * w4.w;
  }
  out[(size_t)b * On + o] = acc + bout[o];
}

extern "C" void kernel_launch(void* const* d_in, const int* in_sizes, int n_in,
                              void* d_out, int out_size, void* d_ws, size_t ws_size,
                              hipStream_t stream) {
  const float* x     = (const float*)d_in[0];
  const float* h0    = (const float*)d_in[1];
  const float* c0    = (const float*)d_in[2];
  const float* W_ih1 = (const float*)d_in[3];
  const float* W_hh1 = (const float*)d_in[4];
  const float* b_ih1 = (const float*)d_in[5];
  const float* b_hh1 = (const float*)d_in[6];
  const float* W_ih2 = (const float*)d_in[7];
  const float* W_hh2 = (const float*)d_in[8];
  const float* b_ih2 = (const float*)d_in[9];
  const float* b_hh2 = (const float*)d_in[10];
  const float* W_out = (const float*)d_in[11];
  const float* b_out = (const float*)d_in[12];

  float* out    = (float*)d_out;
  float* h2_out = out + (size_t)Bn * On;
  float* c2_out = h2_out + (size_t)Bn * Hn;

  char* w = (char*)d_ws;
  float* c_mid = (float*)(w + OFF_CMID);
  float* h_mid = (float*)(w + OFF_HMID);
  u16*   Wb1   = (u16*)(w + OFF_WB1);
  u16*   Wb2   = (u16*)(w + OFF_WB2);
  u16*   ht1   = (u16*)(w + OFF_HT1);
  u16*   xg    = (u16*)(w + OFF_XG);

  const int nw4 = Gn * Hn / 4;

  hipMemsetAsync(ht1, 0xFF, HT_BYTES, stream);   // trail poison (0xFFFF = NaN sentinel)
  hipMemsetAsync(xg, 0xFF, XG_BYTES, stream);    // xg poison (scan1 polls it)
  cvt_kernel<<<(nw4 + 255) / 256, 256, 0, stream>>>(W_ih1, Wb1, nw4);
  cvt_kernel<<<(nw4 + 255) / 256, 256, 0, stream>>>(W_ih2, Wb2, nw4);

  // Phase 1 (one dispatch): scan1 || proj1 || proj2 (data-polls, in-place xg overwrite).
  mega_full<<<256, 256, 0, stream>>>(x, Wb1, b_ih1, b_hh1, W_hh1, h0, c0,
                                     ht1, xg, Wb2, b_ih2, b_hh2, h_mid, c_mid);
  // Phase 2: ht1 fully dead (proj2 consumed y1) -> re-poison and reuse as layer-2 trail.
  hipMemsetAsync(ht1, 0xFF, HT_BYTES, stream);
  scan_plain<<<NG * NS, 256, 0, stream>>>(xg, W_hh2, h_mid, c_mid, ht1, h2_out, c2_out);
  out_kernel<<<Bn, 128, 0, stream>>>(h2_out, W_out, b_out, out);
}